// Round 4
// baseline (64.941 us; speedup 1.0000x reference)
//
#include <hip/hip_runtime.h>
#include <math.h>

#define NB 32
#define NC 256
#define SH 56
#define SW 56
#define HW 3136      // 56*56
#define HW4 784      // HW/4
#define PERB4 (NC * HW4)   // 200704 float4 per batch image

typedef float nf4 __attribute__((ext_vector_type(4)));   // native vec4 for nt-store

// ---------------------------------------------------------------------------
// Kernel 1: per-(b,p) channel max & mean over C=256.
// ---------------------------------------------------------------------------
__global__ __launch_bounds__(256) void k_reduce(const float4* __restrict__ x,
                                                float4* __restrict__ mx_out,
                                                float4* __restrict__ av_out) {
    __shared__ float4 smax[8][32];
    __shared__ float4 ssum[8][32];
    const int tid = threadIdx.x;
    const int pos = tid & 31;
    const int cg  = tid >> 5;
    const unsigned g = blockIdx.x * 32u + pos;       // global float4 spatial idx
    const int b  = (int)(g / HW4);
    const int p4 = (int)(g - (unsigned)b * HW4);
    const float4* base = x + ((size_t)b * NC) * HW4 + p4 + (size_t)(cg * 32) * HW4;

    const float NEG = -__builtin_inff();
    float4 vmax = make_float4(NEG, NEG, NEG, NEG);
    float4 vsum = make_float4(0.f, 0.f, 0.f, 0.f);
    #pragma unroll 8
    for (int c = 0; c < 32; ++c) {
        float4 v = base[(size_t)c * HW4];
        vmax.x = fmaxf(vmax.x, v.x); vmax.y = fmaxf(vmax.y, v.y);
        vmax.z = fmaxf(vmax.z, v.z); vmax.w = fmaxf(vmax.w, v.w);
        vsum.x += v.x; vsum.y += v.y; vsum.z += v.z; vsum.w += v.w;
    }
    smax[cg][pos] = vmax;
    ssum[cg][pos] = vsum;
    __syncthreads();
    if (tid < 32) {
        float4 m = smax[0][tid];
        float4 s = ssum[0][tid];
        #pragma unroll
        for (int q = 1; q < 8; ++q) {
            float4 mm = smax[q][tid];
            float4 ss = ssum[q][tid];
            m.x = fmaxf(m.x, mm.x); m.y = fmaxf(m.y, mm.y);
            m.z = fmaxf(m.z, mm.z); m.w = fmaxf(m.w, mm.w);
            s.x += ss.x; s.y += ss.y; s.z += ss.z; s.w += ss.w;
        }
        const float r = 1.0f / 256.0f;
        s.x *= r; s.y *= r; s.z *= r; s.w *= r;
        const unsigned go = blockIdx.x * 32u + tid;
        mx_out[go] = m;
        av_out[go] = s;
    }
}

// ---------------------------------------------------------------------------
// Kernel 2: 7x7 conv (2ch->1ch, pad 3) + folded BN + sigmoid -> gate [B][HW].
// ---------------------------------------------------------------------------
__global__ __launch_bounds__(256) void k_conv(const float* __restrict__ mx,
                                              const float* __restrict__ av,
                                              const float* __restrict__ cw,
                                              const float* __restrict__ gamma,
                                              const float* __restrict__ beta,
                                              const float* __restrict__ rmean,
                                              const float* __restrict__ rvar,
                                              float* __restrict__ gate) {
    __shared__ float sw[98];
    __shared__ float sbias;
    const int tid = threadIdx.x;
    const float inv = gamma[0] * rsqrtf(rvar[0] + 1e-5f);
    if (tid < 98) sw[tid] = cw[tid] * inv;
    if (tid == 0) sbias = beta[0] - rmean[0] * inv;
    __syncthreads();

    const int idx = blockIdx.x * 256 + tid;          // over B*HW (exact)
    const int b = idx / HW;
    const int p = idx - b * HW;
    const int h = p / SW;
    const int w = p - h * SW;
    const float* mrow = mx + (size_t)b * HW;
    const float* arow = av + (size_t)b * HW;

    float acc = sbias;
    #pragma unroll
    for (int kh = 0; kh < 7; ++kh) {
        const int hh = h + kh - 3;
        if (hh < 0 || hh >= SH) continue;
        #pragma unroll
        for (int kw = 0; kw < 7; ++kw) {
            const int ww = w + kw - 3;
            if (ww < 0 || ww >= SW) continue;
            const int q = hh * SW + ww;
            acc += mrow[q] * sw[kh * 7 + kw] + arow[q] * sw[49 + kh * 7 + kw];
        }
    }
    gate[idx] = 1.0f / (1.0f + expf(-acc));
}

// ---------------------------------------------------------------------------
// Kernel 3: out = x * gate, linear slabs + LDS-staged gate[b],
// NON-TEMPORAL stores (keep x L3-resident across kernels and replays).
// ---------------------------------------------------------------------------
__global__ __launch_bounds__(256) void k_mul(const float4* __restrict__ x,
                                             const float4* __restrict__ gate4, // [B][HW4]
                                             nf4* __restrict__ out) {
    __shared__ float4 sgate[HW4];                    // 12.5 KB
    const int tid  = threadIdx.x;
    const int b    = blockIdx.x / 49;
    const int slab = blockIdx.x - b * 49;

    for (int i = tid; i < HW4; i += 256)
        sgate[i] = gate4[(size_t)b * HW4 + i];
    __syncthreads();

    const unsigned lbase = (unsigned)slab * 4096u + (unsigned)tid;  // within-b float4 idx
    const size_t   gbase = (size_t)b * PERB4;
    #pragma unroll
    for (int i = 0; i < 16; ++i) {
        const unsigned local = lbase + (unsigned)i * 256u;   // 0..200703
        const unsigned p4    = local % (unsigned)HW4;        // const-mod -> mul/shift
        const float4 g  = sgate[p4];
        const float4 xv = x[gbase + local];
        nf4 r;
        r.x = xv.x * g.x; r.y = xv.y * g.y; r.z = xv.z * g.z; r.w = xv.w * g.w;
        __builtin_nontemporal_store(r, &out[gbase + local]);
    }
}

extern "C" void kernel_launch(void* const* d_in, const int* in_sizes, int n_in,
                              void* d_out, int out_size, void* d_ws, size_t ws_size,
                              hipStream_t stream) {
    const float* x     = (const float*)d_in[0];
    const float* cw    = (const float*)d_in[1];
    const float* gamma = (const float*)d_in[2];
    const float* beta  = (const float*)d_in[3];
    const float* rmean = (const float*)d_in[4];
    const float* rvar  = (const float*)d_in[5];
    float* out = (float*)d_out;

    // Workspace layout (floats): mx [B*HW] | av [B*HW] | gate [B*HW]
    float* mx_p   = (float*)d_ws;
    float* av_p   = mx_p + (size_t)NB * HW;
    float* gate_p = av_p + (size_t)NB * HW;

    k_reduce<<<(NB * HW4) / 32, 256, 0, stream>>>(
        (const float4*)x, (float4*)mx_p, (float4*)av_p);

    k_conv<<<(NB * HW) / 256, 256, 0, stream>>>(
        mx_p, av_p, cw, gamma, beta, rmean, rvar, gate_p);

    k_mul<<<NB * 49, 256, 0, stream>>>(
        (const float4*)x, (const float4*)gate_p, (nf4*)out);
}